// Round 2
// baseline (8374.400 us; speedup 1.0000x reference)
//
#include <hip/hip_runtime.h>
#include <hip/hip_bf16.h>

constexpr int   kN     = 64;    // tokens per window (8x8)
constexpr int   kC     = 180;   // channels
constexpr int   kH     = 6;     // heads
constexpr int   kHD    = 30;    // head dim
constexpr float kScale = 0.18257418583505536f; // 30^-0.5

__device__ __forceinline__ float u2f(unsigned short u) {
    return __uint_as_float(((unsigned int)u) << 16);
}
__device__ __forceinline__ unsigned short f2u(float v) {
    // round-to-nearest-even fp32 -> bf16 bits
    unsigned int x = __float_as_uint(v);
    unsigned int r = (x + 0x7FFFu + ((x >> 16) & 1u)) >> 16;
    return (unsigned short)r;
}

// Kernel 1: one block per window. Per head: QKV (90 channels) -> scores
// (+rel-pos bias + mask) -> softmax -> PV. Writes pre-projection attn output
// (fp32) to `attn_out` (= d_out, used as scratch before kernel 2).
__global__ __launch_bounds__(256) void wmsa_attn_kernel(
    const float* __restrict__ x,
    const float* __restrict__ mask,
    const float* __restrict__ qkv_w,
    const float* __restrict__ qkv_b,
    const float* __restrict__ rpb,
    float* __restrict__ attn_out,
    int nw_per_img)
{
    const int w   = blockIdx.x;
    const int tid = threadIdx.x;

    __shared__ unsigned short xs[kN * kC];   // 23040 B  (x as bf16 bits)
    __shared__ float qh[kN * kHD];           // 7680 B   (scaled q, this head)
    __shared__ float kh[kN * kHD];           // 7680 B
    __shared__ float vh[kN * kHD];           // 7680 B
    __shared__ float sc[kN * kN];            // 16384 B  (scores/probs)
    // total 62464 B < 64 KiB

    // ---- stage x[w] : 64x180 fp32 -> bf16 in LDS, coalesced float4 ----
    const float* xg = x + (size_t)w * (kN * kC);
    for (int i = tid; i < (kN * kC) / 4; i += 256) {
        float4 v = ((const float4*)xg)[i];
        ushort4 u;
        u.x = f2u(v.x); u.y = f2u(v.y); u.z = f2u(v.z); u.w = f2u(v.w);
        ((ushort4*)xs)[i] = u;
    }
    __syncthreads();

    const int wi = w % nw_per_img;
    const int lane_m = tid & 15;   // token sub-index (16 m per group)
    const int lane_c = tid >> 4;   // channel sub-index 0..15

    for (int h = 0; h < kH; ++h) {
        // ---- QKV for this head: channels cl in [0,90) = {q,k,v} x 30 ----
        for (int cb = 0; cb < 6; ++cb) {
            int cl = lane_c + 16 * cb;
            if (cl < 3 * kHD) {
                int which = cl / kHD;          // 0=q 1=k 2=v
                int d     = cl % kHD;
                int gch   = which * kC + h * kHD + d;   // qkv_w row
                const float4*  wr  = (const float4*)(qkv_w + (size_t)gch * kC);
                const ushort4* xr0 = (const ushort4*)(xs + (lane_m +  0) * kC);
                const ushort4* xr1 = (const ushort4*)(xs + (lane_m + 16) * kC);
                const ushort4* xr2 = (const ushort4*)(xs + (lane_m + 32) * kC);
                const ushort4* xr3 = (const ushort4*)(xs + (lane_m + 48) * kC);
                float a0 = 0.f, a1 = 0.f, a2 = 0.f, a3 = 0.f;
                for (int k4 = 0; k4 < kC / 4; ++k4) {
                    float4 wv = wr[k4];
                    ushort4 v0 = xr0[k4];
                    a0 += u2f(v0.x)*wv.x + u2f(v0.y)*wv.y + u2f(v0.z)*wv.z + u2f(v0.w)*wv.w;
                    ushort4 v1 = xr1[k4];
                    a1 += u2f(v1.x)*wv.x + u2f(v1.y)*wv.y + u2f(v1.z)*wv.z + u2f(v1.w)*wv.w;
                    ushort4 v2 = xr2[k4];
                    a2 += u2f(v2.x)*wv.x + u2f(v2.y)*wv.y + u2f(v2.z)*wv.z + u2f(v2.w)*wv.w;
                    ushort4 v3 = xr3[k4];
                    a3 += u2f(v3.x)*wv.x + u2f(v3.y)*wv.y + u2f(v3.z)*wv.z + u2f(v3.w)*wv.w;
                }
                float bias = qkv_b[gch];
                a0 += bias; a1 += bias; a2 += bias; a3 += bias;
                if (which == 0) {
                    qh[(lane_m +  0) * kHD + d] = a0 * kScale;
                    qh[(lane_m + 16) * kHD + d] = a1 * kScale;
                    qh[(lane_m + 32) * kHD + d] = a2 * kScale;
                    qh[(lane_m + 48) * kHD + d] = a3 * kScale;
                } else if (which == 1) {
                    kh[(lane_m +  0) * kHD + d] = a0;
                    kh[(lane_m + 16) * kHD + d] = a1;
                    kh[(lane_m + 32) * kHD + d] = a2;
                    kh[(lane_m + 48) * kHD + d] = a3;
                } else {
                    vh[(lane_m +  0) * kHD + d] = a0;
                    vh[(lane_m + 16) * kHD + d] = a1;
                    vh[(lane_m + 32) * kHD + d] = a2;
                    vh[(lane_m + 48) * kHD + d] = a3;
                }
            }
        }
        __syncthreads();

        // ---- scores = q.k^T + rel-pos bias + mask ----
        for (int idx = tid; idx < kN * kN; idx += 256) {
            int i = idx >> 6, j = idx & 63;
            const float* qr = qh + i * kHD;
            const float* kr = kh + j * kHD;
            float acc = 0.f;
            #pragma unroll
            for (int d = 0; d < kHD; ++d) acc += qr[d] * kr[d];
            int yi = i >> 3, xi = i & 7, yj = j >> 3, xj = j & 7;
            int ridx = (yi - yj + 7) * 15 + (xi - xj + 7);   // [0,225)
            acc += rpb[ridx * kH + h];
            acc += mask[(size_t)wi * (kN * kN) + idx];
            sc[idx] = acc;
        }
        __syncthreads();

        // ---- softmax over j (row per thread, threads 0..63) ----
        if (tid < kN) {
            float* row = sc + tid * kN;
            float mx = row[0];
            #pragma unroll 8
            for (int j = 1; j < kN; ++j) mx = fmaxf(mx, row[j]);
            float s = 0.f;
            #pragma unroll 8
            for (int j = 0; j < kN; ++j) { float e = __expf(row[j] - mx); row[j] = e; s += e; }
            float inv = 1.f / s;
            #pragma unroll 8
            for (int j = 0; j < kN; ++j) row[j] *= inv;
        }
        __syncthreads();

        // ---- out_h = P @ V : 64 x 30, store fp32 to global (pre-proj) ----
        for (int idx = tid; idx < kN * kHD; idx += 256) {
            int m = idx / kHD, d = idx % kHD;
            const float* pr = sc + m * kN;
            float acc = 0.f;
            #pragma unroll 8
            for (int j = 0; j < kN; ++j) acc += pr[j] * vh[j * kHD + d];
            attn_out[(size_t)w * (kN * kC) + m * kC + h * kHD + d] = acc;
        }
        __syncthreads();   // protect qh/kh/vh/sc before next head
    }
}

// Kernel 2: output projection, in-place over d_out. One block per window.
// Stage the 64 attn rows in LDS (fp32), then out = attn @ proj_w^T + b.
__global__ __launch_bounds__(256) void wmsa_proj_kernel(
    float* __restrict__ io,
    const float* __restrict__ proj_w,
    const float* __restrict__ proj_b)
{
    const size_t r0  = (size_t)blockIdx.x * kN;   // first token-row
    const int    tid = threadIdx.x;

    __shared__ float as[kN * kC];   // 46080 B

    float* g = io + r0 * kC;
    for (int i = tid; i < (kN * kC) / 4; i += 256)
        ((float4*)as)[i] = ((const float4*)g)[i];
    __syncthreads();

    const int lane_m = tid & 15;
    const int lane_c = tid >> 4;

    for (int cb = 0; cb < 12; ++cb) {
        int c = lane_c + 16 * cb;   // 0..191
        if (c < kC) {
            const float4* wr  = (const float4*)(proj_w + (size_t)c * kC);
            const float4* ar0 = (const float4*)(as + (lane_m +  0) * kC);
            const float4* ar1 = (const float4*)(as + (lane_m + 16) * kC);
            const float4* ar2 = (const float4*)(as + (lane_m + 32) * kC);
            const float4* ar3 = (const float4*)(as + (lane_m + 48) * kC);
            float a0 = 0.f, a1 = 0.f, a2 = 0.f, a3 = 0.f;
            for (int k4 = 0; k4 < kC / 4; ++k4) {
                float4 wv = wr[k4];
                float4 v0 = ar0[k4];
                a0 += v0.x*wv.x + v0.y*wv.y + v0.z*wv.z + v0.w*wv.w;
                float4 v1 = ar1[k4];
                a1 += v1.x*wv.x + v1.y*wv.y + v1.z*wv.z + v1.w*wv.w;
                float4 v2 = ar2[k4];
                a2 += v2.x*wv.x + v2.y*wv.y + v2.z*wv.z + v2.w*wv.w;
                float4 v3 = ar3[k4];
                a3 += v3.x*wv.x + v3.y*wv.y + v3.z*wv.z + v3.w*wv.w;
            }
            float bias = proj_b[c];
            io[(r0 + lane_m +  0) * kC + c] = a0 + bias;
            io[(r0 + lane_m + 16) * kC + c] = a1 + bias;
            io[(r0 + lane_m + 32) * kC + c] = a2 + bias;
            io[(r0 + lane_m + 48) * kC + c] = a3 + bias;
        }
    }
}

extern "C" void kernel_launch(void* const* d_in, const int* in_sizes, int n_in,
                              void* d_out, int out_size, void* d_ws, size_t ws_size,
                              hipStream_t stream) {
    const float* x      = (const float*)d_in[0];
    const float* mask   = (const float*)d_in[1];
    const float* qkv_w  = (const float*)d_in[2];
    const float* qkv_b  = (const float*)d_in[3];
    const float* proj_w = (const float*)d_in[4];
    const float* proj_b = (const float*)d_in[5];
    const float* rpb    = (const float*)d_in[6];
    float* out = (float*)d_out;

    const int nW         = in_sizes[0] / (kN * kC);     // 8192
    const int nw_per_img = in_sizes[1] / (kN * kN);     // 1024

    wmsa_attn_kernel<<<nW, 256, 0, stream>>>(x, mask, qkv_w, qkv_b, rpb, out, nw_per_img);
    wmsa_proj_kernel<<<nW, 256, 0, stream>>>(out, proj_w, proj_b);
}